// Round 2
// baseline (1723.888 us; speedup 1.0000x reference)
//
#include <hip/hip_runtime.h>
#include <hip/hip_bf16.h>

#define H 320
#define W 320
#define HW (H * W)          // 102400
#define CH 64

// ---------------- bicubic x2 upsample (query 3x160x160 -> 3x320x320) --------
__device__ __forceinline__ float cubw(float t) {
    t = fabsf(t);
    if (t <= 1.f) return (1.25f * t - 2.25f) * t * t + 1.f;        // A=-0.75
    if (t < 2.f)  return -0.75f * (((t - 5.f) * t + 8.f) * t - 4.f);
    return 0.f;
}

__global__ __launch_bounds__(256) void bicubic_k(const float* __restrict__ q,
                                                 float* __restrict__ outp) {
    int idx = blockIdx.x * 256 + threadIdx.x;
    if (idx >= 3 * HW) return;
    int c = idx / HW;
    int r = idx - c * HW;
    int oy = r / W, ox = r - (r / W) * W;
    float sy = oy * 0.5f - 0.25f;
    float sx = ox * 0.5f - 0.25f;
    int iy0 = (int)floorf(sy);
    int ix0 = (int)floorf(sx);
    float wy[4], wx[4];
    int tyi[4], txi[4];
#pragma unroll
    for (int a = 0; a < 4; a++) {
        int ty = iy0 - 1 + a;
        wy[a] = cubw(sy - (float)ty);
        tyi[a] = min(max(ty, 0), 159);
        int tx = ix0 - 1 + a;
        wx[a] = cubw(sx - (float)tx);
        txi[a] = min(max(tx, 0), 159);
    }
    const float* ip = q + c * (160 * 160);
    float o = 0.f;
#pragma unroll
    for (int b = 0; b < 4; b++) {
        float s = 0.f;
#pragma unroll
        for (int a = 0; a < 4; a++) s += wy[a] * ip[tyi[a] * 160 + txi[b]];
        o += wx[b] * s;
    }
    outp[idx] = o;
}

// ---------------- direct conv, scalar-weight, LDS-tiled ---------------------
// ACT: 0 = relu, 1 = leaky-relu(0.2). RES: add residual before activation.
// OCB: output channels per block (COUT=32 total, grid = 400 * 32/OCB).
// Weights are read with block-uniform indices straight from global -> the
// compiler emits s_load into SGPRs, FMAs are v_fmac_f32 v,s,v. No LDS for
// weights (R0 showed the 800 ds_read/ic weight reads choked issue BW).
// Tile row stride 24: wave's 4 rows start at banks {0,24,16,8} -> every bank
// covered exactly 2x -> conflict-free (2-way is free on gfx950).
template <int KS, int CIN, int ACT, bool RES, int OCB>
__global__ __launch_bounds__(256) void conv_k(const float* __restrict__ in,
                                              const float* __restrict__ wgt,
                                              const float* __restrict__ bias,
                                              const float* __restrict__ res,
                                              float* __restrict__ out) {
    constexpr int PAD = KS / 2;
    constexpr int TW = 16 + KS - 1;          // 18 or 20
    constexpr int KS2 = KS * KS;             // 9 or 25
    constexpr int TSTR = 24;                 // padded LDS row stride
    constexpr int ICB = (CIN % 4 == 0) ? 4 : 1;  // input channels per barrier
    __shared__ float tile[ICB][TW * TSTR];

    const int tid = threadIdx.x;
    const int tx = tid & 15, ty = tid >> 4;
    const int pix = blockIdx.x % 400;
    const int oc0 = (blockIdx.x / 400) * OCB;
    const int bx = pix % 20, by = pix / 20;
    const int ox = bx * 16 + tx, oy = by * 16 + ty;

    float acc[OCB];
#pragma unroll
    for (int i = 0; i < OCB; i++) acc[i] = 0.f;

    for (int ic0 = 0; ic0 < CIN; ic0 += ICB) {
        __syncthreads();
        for (int idx = tid; idx < ICB * TW * TW; idx += 256) {
            int icc = idx / (TW * TW);
            int rem = idx - icc * (TW * TW);
            int r = rem / TW, c2 = rem - r * TW;
            int iy = by * 16 - PAD + r;
            int ix = bx * 16 - PAD + c2;
            float v = 0.f;
            if (iy >= 0 && iy < H && ix >= 0 && ix < W)
                v = in[(ic0 + icc) * HW + iy * W + ix];
            tile[icc][r * TSTR + c2] = v;
        }
        __syncthreads();
#pragma unroll
        for (int icc = 0; icc < ICB; ++icc) {
            const int ic = ic0 + icc;
            float iv[KS2];
#pragma unroll
            for (int t = 0; t < KS2; t++)
                iv[t] = tile[icc][(ty + t / KS) * TSTR + tx + t % KS];
#pragma unroll
            for (int oc = 0; oc < OCB; ++oc) {
                const float* wp = wgt + ((oc0 + oc) * CIN + ic) * KS2; // uniform
                float s = 0.f;
#pragma unroll
                for (int t = 0; t < KS2; t++) s += iv[t] * wp[t];
                acc[oc] += s;
            }
        }
    }

    const int p = oy * W + ox;
#pragma unroll
    for (int oc = 0; oc < OCB; ++oc) {
        float v = acc[oc] + bias[oc0 + oc];
        if constexpr (RES) v += res[(oc0 + oc) * HW + p];
        if constexpr (ACT == 0) v = fmaxf(v, 0.f);
        else                    v = (v > 0.f) ? v : 0.2f * v;
        out[(oc0 + oc) * HW + p] = v;
    }
}

// ---------------- 1x1 conv 32->3, +1, clip ----------------------------------
__global__ __launch_bounds__(256) void affine_k(const float* __restrict__ hid,
                                                const float* __restrict__ w,
                                                const float* __restrict__ b,
                                                float* __restrict__ outp) {
    int p = blockIdx.x * 256 + threadIdx.x;
    if (p >= HW) return;
    float a0 = 0.f, a1 = 0.f, a2 = 0.f;
    for (int c = 0; c < 32; c++) {
        float h = hid[c * HW + p];
        a0 += h * w[c];
        a1 += h * w[32 + c];
        a2 += h * w[64 + c];
    }
    a0 = fminf(fmaxf(a0 + b[0] + 1.f, -3.f), 3.f);
    a1 = fminf(fmaxf(a1 + b[1] + 1.f, -3.f), 3.f);
    a2 = fminf(fmaxf(a2 + b[2] + 1.f, -3.f), 3.f);
    outp[p] = a0;
    outp[HW + p] = a1;
    outp[2 * HW + p] = a2;
}

// ---------------- deformable 2x2 bilinear sampling --------------------------
__device__ __forceinline__ int reflmap(int q) {
    int s = q - 1;
    if (s < 0) s = -s;
    else if (s > 319) s = 638 - s;
    return s;
}

__global__ __launch_bounds__(256) void sample_k(const float* __restrict__ x,
                                                const float* __restrict__ aff,
                                                float* __restrict__ outp) {
    int idx = blockIdx.x * 256 + threadIdx.x;   // over 640*640 output pixels
    if (idx >= 640 * 640) return;
    int ow = idx % 640, oh = idx / 640;
    int w = ow >> 1, h = oh >> 1;
    int ky = ow & 1, kx = oh & 1;
    int p = h * W + w;
    float s_x = aff[p];
    float s_y = aff[HW + p];
    float th = (aff[2 * HW + p] - 1.f) * 1.0472f;
    float pnx = kx ? 0.5f : -0.5f;
    float pny = ky ? 0.5f : -0.5f;
    float px = pnx * s_x, py = pny * s_y;
    float st, ct;
    __sincosf(th, &st, &ct);
    float rx = px * ct - py * st;
    float ry = px * st + py * ct;
    float p_x = rx + 0.5f + (float)(h + 1);
    float p_y = ry + 0.5f + (float)(w + 1);
    float ltx = floorf(p_x), lty = floorf(p_y);
    float rbx = ltx + 1.f, rby = lty + 1.f;
    float ltxc = fminf(fmaxf(ltx, 0.f), 321.f);
    float ltyc = fminf(fmaxf(lty, 0.f), 321.f);
    float rbxc = fminf(fmaxf(rbx, 0.f), 321.f);
    float rbyc = fminf(fmaxf(rby, 0.f), 321.f);
    p_x = fminf(fmaxf(p_x, 0.f), 321.f);
    p_y = fminf(fmaxf(p_y, 0.f), 321.f);
    float gx0 = 1.f + ltxc - p_x;
    float gx1 = 1.f - (rbxc - p_x);
    float gy0 = 1.f + ltyc - p_y;
    float gy1 = 1.f - (rbyc - p_y);
    float g_lt = gx0 * gy0, g_rb = gx1 * gy1, g_lb = gx0 * gy1, g_rt = gx1 * gy0;
    int ix0 = reflmap((int)ltxc), ix1 = reflmap((int)rbxc);
    int iy0 = reflmap((int)ltyc), iy1 = reflmap((int)rbyc);
    int o00 = ix0 * W + iy0;
    int o11 = ix1 * W + iy1;
    int o01 = ix0 * W + iy1;
    int o10 = ix1 * W + iy0;
    int obase = oh * 640 + ow;
    for (int c = 0; c < CH; c++) {
        const float* xc = x + c * HW;
        float v = g_lt * xc[o00] + g_rb * xc[o11] + g_lb * xc[o01] + g_rt * xc[o10];
        outp[c * (640 * 640) + obase] = v;
    }
}

// ---------------- launch ----------------------------------------------------
extern "C" void kernel_launch(void* const* d_in, const int* in_sizes, int n_in,
                              void* d_out, int out_size, void* d_ws, size_t ws_size,
                              hipStream_t stream) {
    const float* x       = (const float*)d_in[0];
    const float* query   = (const float*)d_in[1];
    const float* ref     = (const float*)d_in[2];
    const float* conv1_w = (const float*)d_in[3];
    const float* conv1_b = (const float*)d_in[4];
    const float* r1_w1   = (const float*)d_in[5];
    const float* r1_b1   = (const float*)d_in[6];
    const float* r1_w2   = (const float*)d_in[7];
    const float* r1_b2   = (const float*)d_in[8];
    const float* p1_w    = (const float*)d_in[9];
    const float* p1_b    = (const float*)d_in[10];
    const float* pr_w1   = (const float*)d_in[11];
    const float* pr_b1   = (const float*)d_in[12];
    const float* pr_w2   = (const float*)d_in[13];
    const float* pr_b2   = (const float*)d_in[14];
    const float* p2_w    = (const float*)d_in[15];
    const float* p2_b    = (const float*)d_in[16];

    float* outp = (float*)d_out;
    float* ws = (float*)d_ws;

    // small scratch in d_ws (2.4 MB), big intermediates inside d_out
    // (all dead before sample_k rewrites every element of d_out).
    float* qup    = ws;                 // 3*HW
    float* affine = ws + 3 * HW;        // 3*HW
    float* feat   = outp;               // 64*HW   (rf ch 0..31, qf ch 32..63)
    float* B      = outp + 64 * HW;     // 32*HW
    float* C      = outp + 96 * HW;     // 32*HW
    float* D      = outp + 128 * HW;    // 32*HW

    bicubic_k<<<1200, 256, 0, stream>>>(query, qup);

    // qf head (OCB=16 -> 800 blocks for occupancy)
    conv_k<5, 3, 1, false, 16><<<800, 256, 0, stream>>>(qup, conv1_w, conv1_b, nullptr, B);
    conv_k<3, 32, 0, false, 16><<<800, 256, 0, stream>>>(B, r1_w1, r1_b1, nullptr, C);
    conv_k<3, 32, 1, true, 16><<<800, 256, 0, stream>>>(C, r1_w2, r1_b2, B, feat + 32 * HW);

    // rf head
    conv_k<5, 3, 1, false, 16><<<800, 256, 0, stream>>>(ref, conv1_w, conv1_b, nullptr, B);
    conv_k<3, 32, 0, false, 16><<<800, 256, 0, stream>>>(B, r1_w1, r1_b1, nullptr, C);
    conv_k<3, 32, 1, true, 16><<<800, 256, 0, stream>>>(C, r1_w2, r1_b2, B, feat);

    // fusion head
    conv_k<5, 64, 1, false, 16><<<800, 256, 0, stream>>>(feat, p1_w, p1_b, nullptr, B);
    conv_k<3, 32, 0, false, 16><<<800, 256, 0, stream>>>(B, pr_w1, pr_b1, nullptr, C);
    conv_k<3, 32, 1, true, 16><<<800, 256, 0, stream>>>(C, pr_w2, pr_b2, B, D);

    affine_k<<<400, 256, 0, stream>>>(D, p2_w, p2_b, affine);

    sample_k<<<1600, 256, 0, stream>>>(x, affine, outp);
}

// Round 3
// 1359.844 us; speedup vs baseline: 1.2677x; 1.2677x over previous
//
#include <hip/hip_runtime.h>
#include <hip/hip_bf16.h>

#define H 320
#define W 320
#define HW (H * W)          // 102400
#define CH 64

// ---------------- bicubic x2 upsample (query 3x160x160 -> 3x320x320) --------
__device__ __forceinline__ float cubw(float t) {
    t = fabsf(t);
    if (t <= 1.f) return (1.25f * t - 2.25f) * t * t + 1.f;        // A=-0.75
    if (t < 2.f)  return -0.75f * (((t - 5.f) * t + 8.f) * t - 4.f);
    return 0.f;
}

__global__ __launch_bounds__(256) void bicubic_k(const float* __restrict__ q,
                                                 float* __restrict__ outp) {
    int idx = blockIdx.x * 256 + threadIdx.x;
    if (idx >= 3 * HW) return;
    int c = idx / HW;
    int r = idx - c * HW;
    int oy = r / W, ox = r - (r / W) * W;
    float sy = oy * 0.5f - 0.25f;
    float sx = ox * 0.5f - 0.25f;
    int iy0 = (int)floorf(sy);
    int ix0 = (int)floorf(sx);
    float wy[4], wx[4];
    int tyi[4], txi[4];
#pragma unroll
    for (int a = 0; a < 4; a++) {
        int ty = iy0 - 1 + a;
        wy[a] = cubw(sy - (float)ty);
        tyi[a] = min(max(ty, 0), 159);
        int tx = ix0 - 1 + a;
        wx[a] = cubw(sx - (float)tx);
        txi[a] = min(max(tx, 0), 159);
    }
    const float* ip = q + c * (160 * 160);
    float o = 0.f;
#pragma unroll
    for (int b = 0; b < 4; b++) {
        float s = 0.f;
#pragma unroll
        for (int a = 0; a < 4; a++) s += wy[a] * ip[tyi[a] * 160 + txi[b]];
        o += wx[b] * s;
    }
    outp[idx] = o;
}

// ---------------- direct conv, all-LDS inner loop ---------------------------
// R2 post-mortem: scalar weight loads (SMEM) share lgkmcnt with LDS reads and
// return out-of-order -> forced lgkmcnt(0) drains each iteration. Fix: weights
// staged to LDS per ic-chunk (broadcast reads, conflict-free), inner loop is
// ds_read + v_fmac only. 4 px/thread: each weight read feeds 4 FMAs; each
// 6-float row window (ds_read_b64 x3) feeds 2 pixels x KS taps.
// Tile row stride 40 -> wave rows at banks {0,8,16,24} -> 2-way (free).
// ACT: 0 = relu, 1 = leaky-relu(0.2). RES: add residual before activation.
template <int KS, int CIN, int ACT, bool RES>
__global__ __launch_bounds__(256) void conv_k(const float* __restrict__ in,
                                              const float* __restrict__ wgt,
                                              const float* __restrict__ bias,
                                              const float* __restrict__ res,
                                              float* __restrict__ out) {
    constexpr int PAD = KS / 2;
    constexpr int TWX = 32 + KS - 1;         // 36 or 34
    constexpr int TWY = 32 + KS - 1;
    constexpr int TSTR = 40;                 // padded LDS row stride
    constexpr int KS2 = KS * KS;             // 25 or 9
    constexpr int WSTR = (KS2 + 3) & ~3;     // 28 or 12 (16B-aligned oc rows)
    constexpr int ICB = (CIN % 4 == 0) ? 4 : CIN;  // 4, or 3 for first conv
    constexpr int OCB = 8;

    __shared__ float tile[ICB][TWY][TSTR];
    __shared__ float wl[ICB][OCB][WSTR];

    const int tid = threadIdx.x;
    const int tx = tid & 15, ty = tid >> 4;
    const int tileId = blockIdx.x >> 2;       // 100 tiles of 32x32
    const int oc0 = (blockIdx.x & 3) * OCB;
    const int x0 = (tileId % 10) * 32;
    const int y0 = (tileId / 10) * 32;

    // 4 pixels: (2tx, ty), (2tx+1, ty), (2tx, ty+16), (2tx+1, ty+16)
    float acc[OCB][4];
#pragma unroll
    for (int i = 0; i < OCB; i++)
#pragma unroll
        for (int j = 0; j < 4; j++) acc[i][j] = 0.f;

    for (int ic0 = 0; ic0 < CIN; ic0 += ICB) {
        __syncthreads();
        // stage input tile (+halo)
        for (int idx = tid; idx < ICB * TWY * TWX; idx += 256) {
            int icc = idx / (TWY * TWX);
            int rem = idx - icc * (TWY * TWX);
            int r = rem / TWX, c = rem - r * TWX;
            int iy = y0 - PAD + r;
            int ix = x0 - PAD + c;
            float v = 0.f;
            if (iy >= 0 && iy < H && ix >= 0 && ix < W)
                v = in[(ic0 + icc) * HW + iy * W + ix];
            tile[icc][r][c] = v;
        }
        // stage weight slice for this ic-chunk (vector loads, lane-varying idx)
        for (int idx = tid; idx < ICB * OCB * KS2; idx += 256) {
            int icc = idx / (OCB * KS2);
            int rem = idx - icc * (OCB * KS2);
            int oc = rem / KS2, t = rem - oc * KS2;
            wl[icc][oc][t] = wgt[((oc0 + oc) * CIN + ic0 + icc) * KS2 + t];
        }
        __syncthreads();

#pragma unroll
        for (int icc = 0; icc < ICB; ++icc) {
            float win[2][KS][KS + 1];
#pragma unroll
            for (int h = 0; h < 2; h++)
#pragma unroll
                for (int r = 0; r < KS; r++)
#pragma unroll
                    for (int c = 0; c < KS + 1; c++)
                        win[h][r][c] = tile[icc][ty + 16 * h + r][2 * tx + c];
#pragma unroll
            for (int oc = 0; oc < OCB; ++oc) {
                float wv[KS2];
#pragma unroll
                for (int t = 0; t < KS2; t++) wv[t] = wl[icc][oc][t];
#pragma unroll
                for (int h = 0; h < 2; h++)
#pragma unroll
                    for (int r = 0; r < KS; r++)
#pragma unroll
                        for (int c = 0; c < KS; c++) {
                            acc[oc][2 * h]     += win[h][r][c]     * wv[r * KS + c];
                            acc[oc][2 * h + 1] += win[h][r][c + 1] * wv[r * KS + c];
                        }
            }
        }
    }

    const int col = x0 + 2 * tx;
#pragma unroll
    for (int oc = 0; oc < OCB; ++oc) {
        float bv = bias[oc0 + oc];
#pragma unroll
        for (int h = 0; h < 2; h++) {
            int row = y0 + ty + 16 * h;
            long base = (long)(oc0 + oc) * HW + row * W + col;
#pragma unroll
            for (int c2 = 0; c2 < 2; c2++) {
                float v = acc[oc][2 * h + c2] + bv;
                if constexpr (RES) v += res[base + c2];
                if constexpr (ACT == 0) v = fmaxf(v, 0.f);
                else                    v = (v > 0.f) ? v : 0.2f * v;
                out[base + c2] = v;
            }
        }
    }
}

// ---------------- 1x1 conv 32->3, +1, clip ----------------------------------
__global__ __launch_bounds__(256) void affine_k(const float* __restrict__ hid,
                                                const float* __restrict__ w,
                                                const float* __restrict__ b,
                                                float* __restrict__ outp) {
    int p = blockIdx.x * 256 + threadIdx.x;
    if (p >= HW) return;
    float a0 = 0.f, a1 = 0.f, a2 = 0.f;
    for (int c = 0; c < 32; c++) {
        float h = hid[c * HW + p];
        a0 += h * w[c];
        a1 += h * w[32 + c];
        a2 += h * w[64 + c];
    }
    a0 = fminf(fmaxf(a0 + b[0] + 1.f, -3.f), 3.f);
    a1 = fminf(fmaxf(a1 + b[1] + 1.f, -3.f), 3.f);
    a2 = fminf(fmaxf(a2 + b[2] + 1.f, -3.f), 3.f);
    outp[p] = a0;
    outp[HW + p] = a1;
    outp[2 * HW + p] = a2;
}

// ---------------- deformable 2x2 bilinear sampling --------------------------
__device__ __forceinline__ int reflmap(int q) {
    int s = q - 1;
    if (s < 0) s = -s;
    else if (s > 319) s = 638 - s;
    return s;
}

__global__ __launch_bounds__(256) void sample_k(const float* __restrict__ x,
                                                const float* __restrict__ aff,
                                                float* __restrict__ outp) {
    int idx = blockIdx.x * 256 + threadIdx.x;   // over 640*640 output pixels
    if (idx >= 640 * 640) return;
    int ow = idx % 640, oh = idx / 640;
    int w = ow >> 1, h = oh >> 1;
    int ky = ow & 1, kx = oh & 1;
    int p = h * W + w;
    float s_x = aff[p];
    float s_y = aff[HW + p];
    float th = (aff[2 * HW + p] - 1.f) * 1.0472f;
    float pnx = kx ? 0.5f : -0.5f;
    float pny = ky ? 0.5f : -0.5f;
    float px = pnx * s_x, py = pny * s_y;
    float st, ct;
    __sincosf(th, &st, &ct);
    float rx = px * ct - py * st;
    float ry = px * st + py * ct;
    float p_x = rx + 0.5f + (float)(h + 1);
    float p_y = ry + 0.5f + (float)(w + 1);
    float ltx = floorf(p_x), lty = floorf(p_y);
    float rbx = ltx + 1.f, rby = lty + 1.f;
    float ltxc = fminf(fmaxf(ltx, 0.f), 321.f);
    float ltyc = fminf(fmaxf(lty, 0.f), 321.f);
    float rbxc = fminf(fmaxf(rbx, 0.f), 321.f);
    float rbyc = fminf(fmaxf(rby, 0.f), 321.f);
    p_x = fminf(fmaxf(p_x, 0.f), 321.f);
    p_y = fminf(fmaxf(p_y, 0.f), 321.f);
    float gx0 = 1.f + ltxc - p_x;
    float gx1 = 1.f - (rbxc - p_x);
    float gy0 = 1.f + ltyc - p_y;
    float gy1 = 1.f - (rbyc - p_y);
    float g_lt = gx0 * gy0, g_rb = gx1 * gy1, g_lb = gx0 * gy1, g_rt = gx1 * gy0;
    int ix0 = reflmap((int)ltxc), ix1 = reflmap((int)rbxc);
    int iy0 = reflmap((int)ltyc), iy1 = reflmap((int)rbyc);
    int o00 = ix0 * W + iy0;
    int o11 = ix1 * W + iy1;
    int o01 = ix0 * W + iy1;
    int o10 = ix1 * W + iy0;
    int obase = oh * 640 + ow;
    for (int c = 0; c < CH; c++) {
        const float* xc = x + c * HW;
        float v = g_lt * xc[o00] + g_rb * xc[o11] + g_lb * xc[o01] + g_rt * xc[o10];
        outp[c * (640 * 640) + obase] = v;
    }
}

// ---------------- launch ----------------------------------------------------
extern "C" void kernel_launch(void* const* d_in, const int* in_sizes, int n_in,
                              void* d_out, int out_size, void* d_ws, size_t ws_size,
                              hipStream_t stream) {
    const float* x       = (const float*)d_in[0];
    const float* query   = (const float*)d_in[1];
    const float* ref     = (const float*)d_in[2];
    const float* conv1_w = (const float*)d_in[3];
    const float* conv1_b = (const float*)d_in[4];
    const float* r1_w1   = (const float*)d_in[5];
    const float* r1_b1   = (const float*)d_in[6];
    const float* r1_w2   = (const float*)d_in[7];
    const float* r1_b2   = (const float*)d_in[8];
    const float* p1_w    = (const float*)d_in[9];
    const float* p1_b    = (const float*)d_in[10];
    const float* pr_w1   = (const float*)d_in[11];
    const float* pr_b1   = (const float*)d_in[12];
    const float* pr_w2   = (const float*)d_in[13];
    const float* pr_b2   = (const float*)d_in[14];
    const float* p2_w    = (const float*)d_in[15];
    const float* p2_b    = (const float*)d_in[16];

    float* outp = (float*)d_out;
    float* ws = (float*)d_ws;

    // small scratch in d_ws (2.4 MB), big intermediates inside d_out
    // (all dead before sample_k rewrites every element of d_out).
    float* qup    = ws;                 // 3*HW
    float* affine = ws + 3 * HW;        // 3*HW
    float* feat   = outp;               // 64*HW   (rf ch 0..31, qf ch 32..63)
    float* B      = outp + 64 * HW;     // 32*HW
    float* C      = outp + 96 * HW;     // 32*HW
    float* D      = outp + 128 * HW;    // 32*HW

    bicubic_k<<<1200, 256, 0, stream>>>(query, qup);

    // qf head (grid = 100 pixel tiles x 4 oc-groups)
    conv_k<5, 3, 1, false><<<400, 256, 0, stream>>>(qup, conv1_w, conv1_b, nullptr, B);
    conv_k<3, 32, 0, false><<<400, 256, 0, stream>>>(B, r1_w1, r1_b1, nullptr, C);
    conv_k<3, 32, 1, true><<<400, 256, 0, stream>>>(C, r1_w2, r1_b2, B, feat + 32 * HW);

    // rf head
    conv_k<5, 3, 1, false><<<400, 256, 0, stream>>>(ref, conv1_w, conv1_b, nullptr, B);
    conv_k<3, 32, 0, false><<<400, 256, 0, stream>>>(B, r1_w1, r1_b1, nullptr, C);
    conv_k<3, 32, 1, true><<<400, 256, 0, stream>>>(C, r1_w2, r1_b2, B, feat);

    // fusion head
    conv_k<5, 64, 1, false><<<400, 256, 0, stream>>>(feat, p1_w, p1_b, nullptr, B);
    conv_k<3, 32, 0, false><<<400, 256, 0, stream>>>(B, pr_w1, pr_b1, nullptr, C);
    conv_k<3, 32, 1, true><<<400, 256, 0, stream>>>(C, pr_w2, pr_b2, B, D);

    affine_k<<<400, 256, 0, stream>>>(D, p2_w, p2_b, affine);

    sample_k<<<1600, 256, 0, stream>>>(x, affine, outp);
}

// Round 4
// 1111.635 us; speedup vs baseline: 1.5508x; 1.2233x over previous
//
#include <hip/hip_runtime.h>
#include <hip/hip_bf16.h>

#define H 320
#define W 320
#define HW (H * W)          // 102400
#define CH 64

// ---------------- bicubic x2 upsample (query 3x160x160 -> 3x320x320) --------
__device__ __forceinline__ float cubw(float t) {
    t = fabsf(t);
    if (t <= 1.f) return (1.25f * t - 2.25f) * t * t + 1.f;        // A=-0.75
    if (t < 2.f)  return -0.75f * (((t - 5.f) * t + 8.f) * t - 4.f);
    return 0.f;
}

__global__ __launch_bounds__(256) void bicubic_k(const float* __restrict__ q,
                                                 float* __restrict__ outp) {
    int idx = blockIdx.x * 256 + threadIdx.x;
    if (idx >= 3 * HW) return;
    int c = idx / HW;
    int r = idx - c * HW;
    int oy = r / W, ox = r - (r / W) * W;
    float sy = oy * 0.5f - 0.25f;
    float sx = ox * 0.5f - 0.25f;
    int iy0 = (int)floorf(sy);
    int ix0 = (int)floorf(sx);
    float wy[4], wx[4];
    int tyi[4], txi[4];
#pragma unroll
    for (int a = 0; a < 4; a++) {
        int ty = iy0 - 1 + a;
        wy[a] = cubw(sy - (float)ty);
        tyi[a] = min(max(ty, 0), 159);
        int tx = ix0 - 1 + a;
        wx[a] = cubw(sx - (float)tx);
        txi[a] = min(max(tx, 0), 159);
    }
    const float* ip = q + c * (160 * 160);
    float o = 0.f;
#pragma unroll
    for (int b = 0; b < 4; b++) {
        float s = 0.f;
#pragma unroll
        for (int a = 0; a < 4; a++) s += wy[a] * ip[tyi[a] * 160 + txi[b]];
        o += wx[b] * s;
    }
    outp[idx] = o;
}

// ---------------- direct conv, all-LDS inner loop ---------------------------
// R3 post-mortem: 400-block grid starved the chip (occupancy 9.4%) and
// TSTR=40 gave 4-way bank conflicts (rows at bank offsets {0,8,16,24} with
// even-only column strides). Fixes:
//  - OCB=4, 8 oc-groups (fast-varying) x 100 tiles = 800 blocks (~3/CU).
//  - ODD row stride (37 / 35): wave rows at alternating bank parity -> <=2
//    lanes/bank = free. Window reads are b32 (same LDS-pipe cycles as b64).
//  - weights via LDS broadcast (same-address = conflict-free), never SMEM
//    in the loop (R2: SMEM shares lgkmcnt, out-of-order -> full drains).
// ACT: 0 = relu, 1 = leaky-relu(0.2). RES: add residual before activation.
template <int KS, int CIN, int ACT, bool RES>
__global__ __launch_bounds__(256, 3) void conv_k(const float* __restrict__ in,
                                                 const float* __restrict__ wgt,
                                                 const float* __restrict__ bias,
                                                 const float* __restrict__ res,
                                                 float* __restrict__ out) {
    constexpr int PAD = KS / 2;
    constexpr int TWX = 32 + KS - 1;         // 36 or 34
    constexpr int TWY = 32 + KS - 1;
    constexpr int TSTR = TWX + 1;            // 37 or 35 (odd!)
    constexpr int KS2 = KS * KS;             // 25 or 9
    constexpr int WSTR = (KS2 + 3) & ~3;     // 28 or 12 (16B-aligned oc rows)
    constexpr int ICB = (CIN % 4 == 0) ? 4 : CIN;  // 4, or 3 for first conv
    constexpr int OCB = 4;

    __shared__ float tile[ICB][TWY][TSTR];
    __shared__ float wl[ICB][OCB][WSTR];

    const int tid = threadIdx.x;
    const int tx = tid & 15, ty = tid >> 4;
    const int tileId = blockIdx.x >> 3;       // 100 tiles of 32x32
    const int oc0 = (blockIdx.x & 7) * OCB;   // oc-group fast-varying: L2 reuse
    const int x0 = (tileId % 10) * 32;
    const int y0 = (tileId / 10) * 32;

    // 4 pixels: (2tx, ty), (2tx+1, ty), (2tx, ty+16), (2tx+1, ty+16)
    float acc[OCB][4];
#pragma unroll
    for (int i = 0; i < OCB; i++)
#pragma unroll
        for (int j = 0; j < 4; j++) acc[i][j] = 0.f;

    for (int ic0 = 0; ic0 < CIN; ic0 += ICB) {
        __syncthreads();
        // stage input tile (+halo)
        for (int idx = tid; idx < ICB * TWY * TWX; idx += 256) {
            int icc = idx / (TWY * TWX);
            int rem = idx - icc * (TWY * TWX);
            int r = rem / TWX, c = rem - r * TWX;
            int iy = y0 - PAD + r;
            int ix = x0 - PAD + c;
            float v = 0.f;
            if (iy >= 0 && iy < H && ix >= 0 && ix < W)
                v = in[(ic0 + icc) * HW + iy * W + ix];
            tile[icc][r][c] = v;
        }
        // stage weight slice for this ic-chunk
        for (int idx = tid; idx < ICB * OCB * KS2; idx += 256) {
            int icc = idx / (OCB * KS2);
            int rem = idx - icc * (OCB * KS2);
            int oc = rem / KS2, t = rem - oc * KS2;
            wl[icc][oc][t] = wgt[((oc0 + oc) * CIN + ic0 + icc) * KS2 + t];
        }
        __syncthreads();

#pragma unroll
        for (int icc = 0; icc < ICB; ++icc) {
            float win[2][KS][KS + 1];
#pragma unroll
            for (int h = 0; h < 2; h++)
#pragma unroll
                for (int r = 0; r < KS; r++)
#pragma unroll
                    for (int c = 0; c < KS + 1; c++)
                        win[h][r][c] = tile[icc][ty + 16 * h + r][2 * tx + c];
#pragma unroll
            for (int oc = 0; oc < OCB; ++oc) {
                float wv[KS2];
#pragma unroll
                for (int t = 0; t < KS2; t++) wv[t] = wl[icc][oc][t];
#pragma unroll
                for (int h = 0; h < 2; h++)
#pragma unroll
                    for (int r = 0; r < KS; r++)
#pragma unroll
                        for (int c = 0; c < KS; c++) {
                            acc[oc][2 * h]     += win[h][r][c]     * wv[r * KS + c];
                            acc[oc][2 * h + 1] += win[h][r][c + 1] * wv[r * KS + c];
                        }
            }
        }
    }

    const int col = x0 + 2 * tx;
#pragma unroll
    for (int oc = 0; oc < OCB; ++oc) {
        float bv = bias[oc0 + oc];
#pragma unroll
        for (int h = 0; h < 2; h++) {
            int row = y0 + ty + 16 * h;
            long base = (long)(oc0 + oc) * HW + row * W + col;
#pragma unroll
            for (int c2 = 0; c2 < 2; c2++) {
                float v = acc[oc][2 * h + c2] + bv;
                if constexpr (RES) v += res[base + c2];
                if constexpr (ACT == 0) v = fmaxf(v, 0.f);
                else                    v = (v > 0.f) ? v : 0.2f * v;
                out[base + c2] = v;
            }
        }
    }
}

// ---------------- 1x1 conv 32->3, +1, clip ----------------------------------
__global__ __launch_bounds__(256) void affine_k(const float* __restrict__ hid,
                                                const float* __restrict__ w,
                                                const float* __restrict__ b,
                                                float* __restrict__ outp) {
    int p = blockIdx.x * 256 + threadIdx.x;
    if (p >= HW) return;
    float a0 = 0.f, a1 = 0.f, a2 = 0.f;
    for (int c = 0; c < 32; c++) {
        float h = hid[c * HW + p];
        a0 += h * w[c];
        a1 += h * w[32 + c];
        a2 += h * w[64 + c];
    }
    a0 = fminf(fmaxf(a0 + b[0] + 1.f, -3.f), 3.f);
    a1 = fminf(fmaxf(a1 + b[1] + 1.f, -3.f), 3.f);
    a2 = fminf(fmaxf(a2 + b[2] + 1.f, -3.f), 3.f);
    outp[p] = a0;
    outp[HW + p] = a1;
    outp[2 * HW + p] = a2;
}

// ---------------- deformable 2x2 bilinear sampling --------------------------
__device__ __forceinline__ int reflmap(int q) {
    int s = q - 1;
    if (s < 0) s = -s;
    else if (s > 319) s = 638 - s;
    return s;
}

__global__ __launch_bounds__(256) void sample_k(const float* __restrict__ x,
                                                const float* __restrict__ aff,
                                                float* __restrict__ outp) {
    int idx = blockIdx.x * 256 + threadIdx.x;   // over 640*640 output pixels
    if (idx >= 640 * 640) return;
    int ow = idx % 640, oh = idx / 640;
    int w = ow >> 1, h = oh >> 1;
    int ky = ow & 1, kx = oh & 1;
    int p = h * W + w;
    float s_x = aff[p];
    float s_y = aff[HW + p];
    float th = (aff[2 * HW + p] - 1.f) * 1.0472f;
    float pnx = kx ? 0.5f : -0.5f;
    float pny = ky ? 0.5f : -0.5f;
    float px = pnx * s_x, py = pny * s_y;
    float st, ct;
    __sincosf(th, &st, &ct);
    float rx = px * ct - py * st;
    float ry = px * st + py * ct;
    float p_x = rx + 0.5f + (float)(h + 1);
    float p_y = ry + 0.5f + (float)(w + 1);
    float ltx = floorf(p_x), lty = floorf(p_y);
    float rbx = ltx + 1.f, rby = lty + 1.f;
    float ltxc = fminf(fmaxf(ltx, 0.f), 321.f);
    float ltyc = fminf(fmaxf(lty, 0.f), 321.f);
    float rbxc = fminf(fmaxf(rbx, 0.f), 321.f);
    float rbyc = fminf(fmaxf(rby, 0.f), 321.f);
    p_x = fminf(fmaxf(p_x, 0.f), 321.f);
    p_y = fminf(fmaxf(p_y, 0.f), 321.f);
    float gx0 = 1.f + ltxc - p_x;
    float gx1 = 1.f - (rbxc - p_x);
    float gy0 = 1.f + ltyc - p_y;
    float gy1 = 1.f - (rbyc - p_y);
    float g_lt = gx0 * gy0, g_rb = gx1 * gy1, g_lb = gx0 * gy1, g_rt = gx1 * gy0;
    int ix0 = reflmap((int)ltxc), ix1 = reflmap((int)rbxc);
    int iy0 = reflmap((int)ltyc), iy1 = reflmap((int)rbyc);
    int o00 = ix0 * W + iy0;
    int o11 = ix1 * W + iy1;
    int o01 = ix0 * W + iy1;
    int o10 = ix1 * W + iy0;
    int obase = oh * 640 + ow;
    for (int c = 0; c < CH; c++) {
        const float* xc = x + c * HW;
        float v = g_lt * xc[o00] + g_rb * xc[o11] + g_lb * xc[o01] + g_rt * xc[o10];
        outp[c * (640 * 640) + obase] = v;
    }
}

// ---------------- launch ----------------------------------------------------
extern "C" void kernel_launch(void* const* d_in, const int* in_sizes, int n_in,
                              void* d_out, int out_size, void* d_ws, size_t ws_size,
                              hipStream_t stream) {
    const float* x       = (const float*)d_in[0];
    const float* query   = (const float*)d_in[1];
    const float* ref     = (const float*)d_in[2];
    const float* conv1_w = (const float*)d_in[3];
    const float* conv1_b = (const float*)d_in[4];
    const float* r1_w1   = (const float*)d_in[5];
    const float* r1_b1   = (const float*)d_in[6];
    const float* r1_w2   = (const float*)d_in[7];
    const float* r1_b2   = (const float*)d_in[8];
    const float* p1_w    = (const float*)d_in[9];
    const float* p1_b    = (const float*)d_in[10];
    const float* pr_w1   = (const float*)d_in[11];
    const float* pr_b1   = (const float*)d_in[12];
    const float* pr_w2   = (const float*)d_in[13];
    const float* pr_b2   = (const float*)d_in[14];
    const float* p2_w    = (const float*)d_in[15];
    const float* p2_b    = (const float*)d_in[16];

    float* outp = (float*)d_out;
    float* ws = (float*)d_ws;

    // small scratch in d_ws (2.4 MB), big intermediates inside d_out
    // (all dead before sample_k rewrites every element of d_out).
    float* qup    = ws;                 // 3*HW
    float* affine = ws + 3 * HW;        // 3*HW
    float* feat   = outp;               // 64*HW   (rf ch 0..31, qf ch 32..63)
    float* B      = outp + 64 * HW;     // 32*HW
    float* C      = outp + 96 * HW;     // 32*HW
    float* D      = outp + 128 * HW;    // 32*HW

    bicubic_k<<<1200, 256, 0, stream>>>(query, qup);

    // qf head (grid = 100 pixel tiles x 8 oc-groups of 4)
    conv_k<5, 3, 1, false><<<800, 256, 0, stream>>>(qup, conv1_w, conv1_b, nullptr, B);
    conv_k<3, 32, 0, false><<<800, 256, 0, stream>>>(B, r1_w1, r1_b1, nullptr, C);
    conv_k<3, 32, 1, true><<<800, 256, 0, stream>>>(C, r1_w2, r1_b2, B, feat + 32 * HW);

    // rf head
    conv_k<5, 3, 1, false><<<800, 256, 0, stream>>>(ref, conv1_w, conv1_b, nullptr, B);
    conv_k<3, 32, 0, false><<<800, 256, 0, stream>>>(B, r1_w1, r1_b1, nullptr, C);
    conv_k<3, 32, 1, true><<<800, 256, 0, stream>>>(C, r1_w2, r1_b2, B, feat);

    // fusion head
    conv_k<5, 64, 1, false><<<800, 256, 0, stream>>>(feat, p1_w, p1_b, nullptr, B);
    conv_k<3, 32, 0, false><<<800, 256, 0, stream>>>(B, pr_w1, pr_b1, nullptr, C);
    conv_k<3, 32, 1, true><<<800, 256, 0, stream>>>(C, pr_w2, pr_b2, B, D);

    affine_k<<<400, 256, 0, stream>>>(D, p2_w, p2_b, affine);

    sample_k<<<1600, 256, 0, stream>>>(x, affine, outp);
}